// Round 3
// baseline (430.390 us; speedup 1.0000x reference)
//
#include <hip/hip_runtime.h>
#include <cmath>

namespace {

constexpr int B_ = 2;
constexpr int T_ = 2048;
constexpr int C_ = 1024;
constexpr int H_ = 16;
constexpr int D_ = 64;

typedef _Float16 half8 __attribute__((ext_vector_type(8)));
typedef _Float16 half4 __attribute__((ext_vector_type(4)));
typedef float f32x4 __attribute__((ext_vector_type(4)));

__device__ inline f32x4 vmax4(f32x4 a, f32x4 b) {
  f32x4 r;
  r[0] = fmaxf(a[0], b[0]); r[1] = fmaxf(a[1], b[1]);
  r[2] = fmaxf(a[2], b[2]); r[3] = fmaxf(a[3], b[3]);
  return r;
}

__device__ __forceinline__ void gload16(const _Float16* g, _Float16* l) {
  __builtin_amdgcn_global_load_lds(
      (const __attribute__((address_space(1))) unsigned int*)g,
      (__attribute__((address_space(3))) unsigned int*)l, 16, 0, 0);
}

// ---------------------------------------------------------------------------
// Fused cast: 7 fp32 arrays -> f16 (xq,xk,xv: 4M els; Wq,Wk,Wv,Wo: 1M els).
// ---------------------------------------------------------------------------
__global__ __launch_bounds__(256)
void cast7(const float* __restrict__ xq, const float* __restrict__ xk,
           const float* __restrict__ xv, const float* __restrict__ wq,
           const float* __restrict__ wk, const float* __restrict__ wv,
           const float* __restrict__ wo,
           _Float16* __restrict__ dxq, _Float16* __restrict__ dxk,
           _Float16* __restrict__ dxv, _Float16* __restrict__ dwq,
           _Float16* __restrict__ dwk, _Float16* __restrict__ dwv,
           _Float16* __restrict__ dwo) {
  constexpr size_t NX = (size_t)4 << 20;
  constexpr size_t NW = (size_t)1 << 20;
  size_t g = ((size_t)blockIdx.x * 256 + threadIdx.x) * 8;
  const float* s; _Float16* d; size_t off;
  if      (g <     NX)          { s = xq; d = dxq; off = g; }
  else if (g < 2 * NX)          { s = xk; d = dxk; off = g - NX; }
  else if (g < 3 * NX)          { s = xv; d = dxv; off = g - 2 * NX; }
  else if (g < 3 * NX + NW)     { s = wq; d = dwq; off = g - 3 * NX; }
  else if (g < 3 * NX + 2 * NW) { s = wk; d = dwk; off = g - 3 * NX - NW; }
  else if (g < 3 * NX + 3 * NW) { s = wv; d = dwv; off = g - 3 * NX - 2 * NW; }
  else                          { s = wo; d = dwo; off = g - 3 * NX - 3 * NW; }
  const float4 a = *(const float4*)(s + off);
  const float4 b = *(const float4*)(s + off + 4);
  half8 h;
  h[0] = (_Float16)a.x; h[1] = (_Float16)a.y; h[2] = (_Float16)a.z; h[3] = (_Float16)a.w;
  h[4] = (_Float16)b.x; h[5] = (_Float16)b.y; h[6] = (_Float16)b.z; h[7] = (_Float16)b.w;
  *(half8*)(d + off) = h;
}

// ---------------------------------------------------------------------------
// LDS-staged f16 NT GEMM (m97 structure): Y[m][n] = sum_k A[m][k]*W[n][k].
// Tile 128x128, BK=32; 4 waves, each a 64x64 quadrant (4x4 16x16x32 MFMAs).
// mode 0: f16 Y out (z==0 output scaled by qsc: folds the sqrt(D) quirk into
// Q once). mode 2: fp32 out + bias.
// ---------------------------------------------------------------------------
__global__ __launch_bounds__(256, 3)
void gemm_f16nt(const _Float16* __restrict__ A0, const _Float16* __restrict__ A1,
                const _Float16* __restrict__ A2,
                const _Float16* __restrict__ W0, const _Float16* __restrict__ W1,
                const _Float16* __restrict__ W2,
                _Float16* __restrict__ Y0, _Float16* __restrict__ Y1,
                _Float16* __restrict__ Y2,
                float* __restrict__ Yf, const float* __restrict__ bias,
                int K, int N, int mode, float qsc) {
  __shared__ _Float16 sA[128 * 32];
  __shared__ _Float16 sW[128 * 32];

  const int tid  = threadIdx.x;
  const int lane = tid & 63;
  const int w    = tid >> 6;
  const int l15  = lane & 15;
  const int quad = lane >> 4;
  const int z    = blockIdx.z;
  const _Float16* A = (z == 0) ? A0 : (z == 1) ? A1 : A2;
  const _Float16* W = (z == 0) ? W0 : (z == 1) ? W1 : W2;
  _Float16*       Y = (z == 0) ? Y0 : (z == 1) ? Y1 : Y2;

  const int m0 = blockIdx.y * 128;
  const int n0 = blockIdx.x * 128;

  const int Rb  = lane >> 2;
  const int pch = lane & 3;
  const int lch = pch ^ ((Rb >> 1) & 3);
  const int swr = (l15 >> 1) & 3;

  f32x4 acc[4][4];
#pragma unroll
  for (int mt = 0; mt < 4; ++mt)
#pragma unroll
    for (int nt = 0; nt < 4; ++nt)
      acc[mt][nt] = (f32x4){0.f, 0.f, 0.f, 0.f};

  const int wm = (w >> 1) * 64;
  const int wn = (w & 1) * 64;

  for (int k0 = 0; k0 < K; k0 += 32) {
    __syncthreads();
#pragma unroll
    for (int j = 0; j < 2; ++j) {
      const int seg = w * 32 + j * 16;
      gload16(A + (size_t)(m0 + seg + Rb) * K + k0 + lch * 8, &sA[seg * 32]);
      gload16(W + (size_t)(n0 + seg + Rb) * K + k0 + lch * 8, &sW[seg * 32]);
    }
    __syncthreads();

    half8 af[4], wf[4];
#pragma unroll
    for (int mt = 0; mt < 4; ++mt) {
      const int R = wm + mt * 16 + l15;
      af[mt] = *(const half8*)&sA[R * 32 + (quad ^ swr) * 8];
    }
#pragma unroll
    for (int nt = 0; nt < 4; ++nt) {
      const int R = wn + nt * 16 + l15;
      wf[nt] = *(const half8*)&sW[R * 32 + (quad ^ swr) * 8];
    }
#pragma unroll
    for (int mt = 0; mt < 4; ++mt)
#pragma unroll
      for (int nt = 0; nt < 4; ++nt)
        acc[mt][nt] = __builtin_amdgcn_mfma_f32_16x16x32_f16(wf[nt], af[mt], acc[mt][nt], 0, 0, 0);
  }

  const float ysc = (mode == 0 && z == 0) ? qsc : 1.f;
#pragma unroll
  for (int mt = 0; mt < 4; ++mt)
#pragma unroll
    for (int nt = 0; nt < 4; ++nt) {
      const int m = m0 + wm + mt * 16 + l15;
      const int n = n0 + wn + nt * 16 + quad * 4;
      if (mode == 2) {
        float4 v;
        v.x = acc[mt][nt][0] + bias[n + 0];
        v.y = acc[mt][nt][1] + bias[n + 1];
        v.z = acc[mt][nt][2] + bias[n + 2];
        v.w = acc[mt][nt][3] + bias[n + 3];
        *(float4*)(Yf + (size_t)m * N + n) = v;
      } else {
        half4 hv;
#pragma unroll
        for (int r = 0; r < 4; ++r) hv[r] = (_Float16)(acc[mt][nt][r] * ysc);
        *(half4*)(Y + (size_t)m * N + n) = hv;
      }
    }
}

// ---------------------------------------------------------------------------
// V pretranspose: Vh[b][t][c] -> Vt packed per (b,h,kt) 16x64 tile such that
// lane (l15,quad) reads its 4 PV fragments as TWO half8 loads:
//   Vt[(b,h,kt)*1024 + (d&15)*64 + (k>>2)*16 + (d>>4)*4 + (k&3)]
//     = V[b][kt*16+k][h*64+d]
// ---------------------------------------------------------------------------
__global__ __launch_bounds__(256)
void transpose_v(const _Float16* __restrict__ Vh, _Float16* __restrict__ Vt) {
  constexpr int PAD = 1028;
  __shared__ _Float16 tile[16][PAD];
  const int b  = blockIdx.x >> 7;
  const int kt = blockIdx.x & 127;
  const int tid = threadIdx.x;

#pragma unroll
  for (int j = 0; j < 8; ++j) {
    const int ch = tid + 256 * j;
    const int t  = ch >> 7;
    const int c8 = ch & 127;
    *(half8*)&tile[t][c8 * 8] =
        *(const half8*)(Vh + ((size_t)b * T_ + kt * 16 + t) * C_ + c8 * 8);
  }
  __syncthreads();

#pragma unroll
  for (int j = 0; j < 8; ++j) {
    const int cc = tid + 256 * j;
    const int h  = cc >> 7;
    const int d  = (cc >> 1) & 63;
    const int th = (cc & 1) * 8;
    const int c  = h * 64 + d;
    half4 va, vb4;
#pragma unroll
    for (int i = 0; i < 4; ++i) va[i]  = tile[th + i][c];
#pragma unroll
    for (int i = 0; i < 4; ++i) vb4[i] = tile[th + 4 + i][c];
    const size_t base = (((size_t)b * H_ + h) * 128 + kt) * 1024 +
                        (size_t)((d & 15) * 64 + (th >> 2) * 16 + (d >> 4) * 4);
    *(half4*)(Vt + base) = va;
    *(half4*)(Vt + base + 16) = vb4;
  }
}

// ---------------------------------------------------------------------------
// MFMA head-softmax attention v7: XCD-L2-locality mapping.
// There are exactly 8 (batch,split) combos and 8 XCDs; hardware round-robins
// blockIdx over XCDs (xcd = blockIdx&7). Pinning (b,split)=f(xcd) makes every
// block resident on one XCD read the SAME 2MB K-slice + 2MB V-slice -> fits
// the 4MB per-XCD L2, so K/V stream at L2 BW instead of Infinity-Cache BW
// (the measured 8.2 TB/s wall). Q loads and OP stores are non-temporal
// (zero reuse within an XCD) to avoid evicting the K/V slice.
// Tile loop is the r0 (fastest) structure: compiler-scheduled loads.
// Q arrives pre-scaled by sqrt(D)=8 (folded into the projection).
// ---------------------------------------------------------------------------
__global__ __launch_bounds__(256, 2)
void attn_mfma(const _Float16* __restrict__ Qhp, const _Float16* __restrict__ Khp,
               const _Float16* __restrict__ Vtp, _Float16* __restrict__ OP) {
  __shared__ f32x4 red[2][2][4][64];

  const int tid  = threadIdx.x;
  const int lane = tid & 63;
  const int w    = tid >> 6;
  const int l15  = lane & 15;
  const int quad = lane >> 4;
  const int cell = quad * 16 + l15;

  // XCD-locality mapping (see header comment)
  const int xcd   = blockIdx.x & 7;
  const int qi    = blockIdx.x >> 3;   // 0..127
  const int b     = xcd & 1;
  const int split = xcd >> 1;          // 0..3
  const int q0    = qi << 4;

  const size_t qrow = ((size_t)b * T_ + q0 + l15) * C_;

  // hoisted Q fragments (loop-invariant): 8 half8 = 32 VGPR; non-temporal
  half8 qh[4][2];
#pragma unroll
  for (int hl = 0; hl < 4; ++hl)
#pragma unroll
    for (int kk = 0; kk < 2; ++kk)
      qh[hl][kk] = __builtin_nontemporal_load(
          (const half8*)(Qhp + qrow + (w * 4 + hl) * 64 + kk * 32 + quad * 8));

  f32x4 oacc[4][4];
#pragma unroll
  for (int hl = 0; hl < 4; ++hl)
#pragma unroll
    for (int mt = 0; mt < 4; ++mt)
      oacc[hl][mt] = (f32x4){0.f, 0.f, 0.f, 0.f};

  const int kpb  = T_ / 4;
  const int k_lo = split * kpb;
  const int jt   = kpb / 16;           // 32

  // per-lane V base: head block (w*4), lane offset folded in
  const _Float16* vbase = Vtp + ((size_t)b * H_ + w * 4) * (128 * 1024) +
                          (size_t)(l15 * 64 + quad * 16);

  for (int j = 0; j < jt; ++j) {
    const int k0 = k_lo + j * 16;
    const int kt = k0 >> 4;
    const int p  = j & 1;
    const size_t krow = ((size_t)b * T_ + k0 + l15) * C_;

    // K + V fragment loads (compiler-scheduled; L2-resident by construction)
    half8 akh[4][2];
    half8 avh[4][2];
#pragma unroll
    for (int hl = 0; hl < 4; ++hl)
#pragma unroll
      for (int kk = 0; kk < 2; ++kk)
        akh[hl][kk] = *(const half8*)(Khp + krow + (w * 4 + hl) * 64 + kk * 32 + quad * 8);
#pragma unroll
    for (int hl = 0; hl < 4; ++hl) {
      const _Float16* vb = vbase + (size_t)hl * (128 * 1024) + (size_t)kt * 1024;
      avh[hl][0] = *(const half8*)(vb);
      avh[hl][1] = *(const half8*)(vb + 8);
    }

    // S^T = K Q^T (Q pre-scaled by sqrt(D))
    f32x4 s[4];
#pragma unroll
    for (int hl = 0; hl < 4; ++hl) s[hl] = (f32x4){0.f, 0.f, 0.f, 0.f};
    __builtin_amdgcn_s_setprio(1);
#pragma unroll
    for (int hl = 0; hl < 4; ++hl)
#pragma unroll
      for (int kk = 0; kk < 2; ++kk)
        s[hl] = __builtin_amdgcn_mfma_f32_16x16x32_f16(akh[hl][kk], qh[hl][kk], s[hl], 0, 0, 0);
    __builtin_amdgcn_s_setprio(0);

    // head-softmax, ping-pong LDS: 2 barriers/tile
    red[p][0][w][cell] = vmax4(vmax4(s[0], s[1]), vmax4(s[2], s[3]));
    __syncthreads();
    const f32x4 gmax = vmax4(vmax4(red[p][0][0][cell], red[p][0][1][cell]),
                             vmax4(red[p][0][2][cell], red[p][0][3][cell]));
    f32x4 ps = (f32x4){0.f, 0.f, 0.f, 0.f};
#pragma unroll
    for (int hl = 0; hl < 4; ++hl)
#pragma unroll
      for (int r = 0; r < 4; ++r) {
        const float ev = __expf(s[hl][r] - gmax[r]);
        s[hl][r] = ev;
        ps[r] += ev;
      }
    red[p][1][w][cell] = ps;
    __syncthreads();
    const f32x4 gs = red[p][1][0][cell] + red[p][1][1][cell] +
                     red[p][1][2][cell] + red[p][1][3][cell];
    f32x4 inv;
#pragma unroll
    for (int r = 0; r < 4; ++r) inv[r] = 1.f / gs[r];

    half4 pf[4];
#pragma unroll
    for (int hl = 0; hl < 4; ++hl)
#pragma unroll
      for (int r = 0; r < 4; ++r)
        pf[hl][r] = (_Float16)(s[hl][r] * inv[r]);

    // O^T += V^T P^T
    __builtin_amdgcn_s_setprio(1);
#pragma unroll
    for (int hl = 0; hl < 4; ++hl) {
      const half4 v0 = __builtin_shufflevector(avh[hl][0], avh[hl][0], 0, 1, 2, 3);
      const half4 v1 = __builtin_shufflevector(avh[hl][0], avh[hl][0], 4, 5, 6, 7);
      const half4 v2 = __builtin_shufflevector(avh[hl][1], avh[hl][1], 0, 1, 2, 3);
      const half4 v3 = __builtin_shufflevector(avh[hl][1], avh[hl][1], 4, 5, 6, 7);
      oacc[hl][0] = __builtin_amdgcn_mfma_f32_16x16x16f16(v0, pf[hl], oacc[hl][0], 0, 0, 0);
      oacc[hl][1] = __builtin_amdgcn_mfma_f32_16x16x16f16(v1, pf[hl], oacc[hl][1], 0, 0, 0);
      oacc[hl][2] = __builtin_amdgcn_mfma_f32_16x16x16f16(v2, pf[hl], oacc[hl][2], 0, 0, 0);
      oacc[hl][3] = __builtin_amdgcn_mfma_f32_16x16x16f16(v3, pf[hl], oacc[hl][3], 0, 0, 0);
    }
    __builtin_amdgcn_s_setprio(0);
  }

  _Float16* op = OP + (size_t)split * ((size_t)B_ * T_ * C_);
  const size_t orow = ((size_t)b * T_ + q0 + l15) * C_;
#pragma unroll
  for (int hl = 0; hl < 4; ++hl)
#pragma unroll
    for (int mt = 0; mt < 4; ++mt) {
      half4 hv;
#pragma unroll
      for (int r = 0; r < 4; ++r) hv[r] = (_Float16)oacc[hl][mt][r];
      __builtin_nontemporal_store(
          hv, (half4*)(op + orow + (w * 4 + hl) * 64 + mt * 16 + quad * 4));
    }
}

// ---------------------------------------------------------------------------
// AOh = (f16) sum over splits of f16 OP[s]  (fp32 accumulate)
// ---------------------------------------------------------------------------
__global__ __launch_bounds__(256)
void reduce_oh(const _Float16* __restrict__ OP, _Float16* __restrict__ AOh,
               int nsplit, size_t n) {
  const size_t i = ((size_t)blockIdx.x * 256 + threadIdx.x) * 8;
  float a[8] = {};
  for (int s = 0; s < nsplit; ++s) {
    const half8 v = *(const half8*)(OP + (size_t)s * n + i);
#pragma unroll
    for (int r = 0; r < 8; ++r) a[r] += (float)v[r];
  }
  half8 o;
#pragma unroll
  for (int r = 0; r < 8; ++r) o[r] = (_Float16)a[r];
  *(half8*)(AOh + i) = o;
}

}  // namespace

extern "C" void kernel_launch(void* const* d_in, const int* in_sizes, int n_in,
                              void* d_out, int out_size, void* d_ws, size_t ws_size,
                              hipStream_t stream) {
  const float* xq = (const float*)d_in[0];
  const float* xk = (const float*)d_in[1];
  const float* xv = (const float*)d_in[2];
  const float* Wq = (const float*)d_in[3];
  const float* Wk = (const float*)d_in[4];
  const float* Wv = (const float*)d_in[5];
  const float* Wo = (const float*)d_in[6];
  const float* bo = (const float*)d_in[7];
  float* out = (float*)d_out;

  const size_t MB   = 1ull << 20;
  const size_t nBTC = (size_t)B_ * T_ * C_;  // 4M elements

  char* wsb = (char*)d_ws;
  _Float16* Qh  = (_Float16*)(wsb + 0 * MB);
  _Float16* Kh  = (_Float16*)(wsb + 8 * MB);
  _Float16* Vt  = (_Float16*)(wsb + 16 * MB);
  _Float16* vh  = (_Float16*)(wsb + 24 * MB);
  _Float16* AOh = (_Float16*)(wsb + 24 * MB);
  _Float16* xqh = (_Float16*)(wsb + 32 * MB);
  _Float16* xkh = (_Float16*)(wsb + 40 * MB);
  _Float16* xvh = (_Float16*)(wsb + 48 * MB);
  _Float16* OP  = (_Float16*)(wsb + 32 * MB);
  _Float16* Wqh = (_Float16*)(wsb + 64 * MB);
  _Float16* Wkh = (_Float16*)(wsb + 66 * MB);
  _Float16* Wvh = (_Float16*)(wsb + 68 * MB);
  _Float16* Woh = (_Float16*)(wsb + 70 * MB);

  const int nsplit = 4;
  const int M = B_ * T_;                     // 4096
  dim3 blk(256);

  // 1) cast all 7 fp32 inputs to f16 (16M elements)
  cast7<<<dim3(8192), blk, 0, stream>>>(xq, xk, xv, Wq, Wk, Wv, Wo,
                                        xqh, xkh, xvh, Wqh, Wkh, Wvh, Woh);

  // 2) three projections, z-batched; Q pre-scaled by sqrt(D)=8 (quirk)
  gemm_f16nt<<<dim3(C_ / 128, M / 128, 3), blk, 0, stream>>>(
      xqh, xkh, xvh, Wqh, Wkh, Wvh, Qh, Kh, vh,
      nullptr, nullptr, C_, C_, 0, 8.f);

  // 3) V pretranspose (packed PV-fragment layout)
  transpose_v<<<dim3(B_ * 128), blk, 0, stream>>>(vh, Vt);

  // 4) fused head-softmax attention (split-k x4, XCD-L2-local mapping)
  attn_mfma<<<dim3(B_ * (T_ / 16) * nsplit), blk, 0, stream>>>(Qh, Kh, Vt, OP);

  // 5) split reduction -> f16 AO
  reduce_oh<<<dim3((unsigned)(nBTC / 2048)), blk, 0, stream>>>(OP, AOh, nsplit, nBTC);

  // 6) output projection + bias -> fp32 out
  gemm_f16nt<<<dim3(C_ / 128, M / 128, 1), blk, 0, stream>>>(
      AOh, nullptr, nullptr, Woh, nullptr, nullptr, nullptr, nullptr, nullptr,
      out, bo, C_, C_, 2, 1.f);
}

// Round 4
// 423.427 us; speedup vs baseline: 1.0164x; 1.0164x over previous
//
#include <hip/hip_runtime.h>
#include <cmath>

namespace {

constexpr int B_ = 2;
constexpr int T_ = 2048;
constexpr int C_ = 1024;
constexpr int H_ = 16;
constexpr int D_ = 64;

typedef _Float16 half8 __attribute__((ext_vector_type(8)));
typedef _Float16 half4 __attribute__((ext_vector_type(4)));
typedef float f32x4 __attribute__((ext_vector_type(4)));

__device__ inline f32x4 vmax4(f32x4 a, f32x4 b) {
  f32x4 r;
  r[0] = fmaxf(a[0], b[0]); r[1] = fmaxf(a[1], b[1]);
  r[2] = fmaxf(a[2], b[2]); r[3] = fmaxf(a[3], b[3]);
  return r;
}

__device__ __forceinline__ void gload16(const _Float16* g, _Float16* l) {
  __builtin_amdgcn_global_load_lds(
      (const __attribute__((address_space(1))) unsigned int*)g,
      (__attribute__((address_space(3))) unsigned int*)l, 16, 0, 0);
}

// LDS-visibility barrier WITHOUT the vmcnt drain of __syncthreads().
__device__ __forceinline__ void lds_barrier() {
  asm volatile("s_waitcnt lgkmcnt(0)" ::: "memory");
  __builtin_amdgcn_s_barrier();
}

// ---------------------------------------------------------------------------
// Fused cast: 7 fp32 arrays -> f16 (xq,xk,xv: 4M els; Wq,Wk,Wv,Wo: 1M els).
// ---------------------------------------------------------------------------
__global__ __launch_bounds__(256)
void cast7(const float* __restrict__ xq, const float* __restrict__ xk,
           const float* __restrict__ xv, const float* __restrict__ wq,
           const float* __restrict__ wk, const float* __restrict__ wv,
           const float* __restrict__ wo,
           _Float16* __restrict__ dxq, _Float16* __restrict__ dxk,
           _Float16* __restrict__ dxv, _Float16* __restrict__ dwq,
           _Float16* __restrict__ dwk, _Float16* __restrict__ dwv,
           _Float16* __restrict__ dwo) {
  constexpr size_t NX = (size_t)4 << 20;
  constexpr size_t NW = (size_t)1 << 20;
  size_t g = ((size_t)blockIdx.x * 256 + threadIdx.x) * 8;
  const float* s; _Float16* d; size_t off;
  if      (g <     NX)          { s = xq; d = dxq; off = g; }
  else if (g < 2 * NX)          { s = xk; d = dxk; off = g - NX; }
  else if (g < 3 * NX)          { s = xv; d = dxv; off = g - 2 * NX; }
  else if (g < 3 * NX + NW)     { s = wq; d = dwq; off = g - 3 * NX; }
  else if (g < 3 * NX + 2 * NW) { s = wk; d = dwk; off = g - 3 * NX - NW; }
  else if (g < 3 * NX + 3 * NW) { s = wv; d = dwv; off = g - 3 * NX - 2 * NW; }
  else                          { s = wo; d = dwo; off = g - 3 * NX - 3 * NW; }
  const float4 a = *(const float4*)(s + off);
  const float4 b = *(const float4*)(s + off + 4);
  half8 h;
  h[0] = (_Float16)a.x; h[1] = (_Float16)a.y; h[2] = (_Float16)a.z; h[3] = (_Float16)a.w;
  h[4] = (_Float16)b.x; h[5] = (_Float16)b.y; h[6] = (_Float16)b.z; h[7] = (_Float16)b.w;
  *(half8*)(d + off) = h;
}

// ---------------------------------------------------------------------------
// LDS-staged f16 NT GEMM (m97 structure): Y[m][n] = sum_k A[m][k]*W[n][k].
// Tile 128x128, BK=32; 4 waves, each a 64x64 quadrant (4x4 16x16x32 MFMAs).
// mode 0: f16 Y out (z==0 output scaled by qsc: folds the sqrt(D) quirk into
// Q once). mode 2: fp32 out + bias.
// ---------------------------------------------------------------------------
__global__ __launch_bounds__(256, 3)
void gemm_f16nt(const _Float16* __restrict__ A0, const _Float16* __restrict__ A1,
                const _Float16* __restrict__ A2,
                const _Float16* __restrict__ W0, const _Float16* __restrict__ W1,
                const _Float16* __restrict__ W2,
                _Float16* __restrict__ Y0, _Float16* __restrict__ Y1,
                _Float16* __restrict__ Y2,
                float* __restrict__ Yf, const float* __restrict__ bias,
                int K, int N, int mode, float qsc) {
  __shared__ _Float16 sA[128 * 32];
  __shared__ _Float16 sW[128 * 32];

  const int tid  = threadIdx.x;
  const int lane = tid & 63;
  const int w    = tid >> 6;
  const int l15  = lane & 15;
  const int quad = lane >> 4;
  const int z    = blockIdx.z;
  const _Float16* A = (z == 0) ? A0 : (z == 1) ? A1 : A2;
  const _Float16* W = (z == 0) ? W0 : (z == 1) ? W1 : W2;
  _Float16*       Y = (z == 0) ? Y0 : (z == 1) ? Y1 : Y2;

  const int m0 = blockIdx.y * 128;
  const int n0 = blockIdx.x * 128;

  const int Rb  = lane >> 2;
  const int pch = lane & 3;
  const int lch = pch ^ ((Rb >> 1) & 3);
  const int swr = (l15 >> 1) & 3;

  f32x4 acc[4][4];
#pragma unroll
  for (int mt = 0; mt < 4; ++mt)
#pragma unroll
    for (int nt = 0; nt < 4; ++nt)
      acc[mt][nt] = (f32x4){0.f, 0.f, 0.f, 0.f};

  const int wm = (w >> 1) * 64;
  const int wn = (w & 1) * 64;

  for (int k0 = 0; k0 < K; k0 += 32) {
    __syncthreads();
#pragma unroll
    for (int j = 0; j < 2; ++j) {
      const int seg = w * 32 + j * 16;
      gload16(A + (size_t)(m0 + seg + Rb) * K + k0 + lch * 8, &sA[seg * 32]);
      gload16(W + (size_t)(n0 + seg + Rb) * K + k0 + lch * 8, &sW[seg * 32]);
    }
    __syncthreads();

    half8 af[4], wf[4];
#pragma unroll
    for (int mt = 0; mt < 4; ++mt) {
      const int R = wm + mt * 16 + l15;
      af[mt] = *(const half8*)&sA[R * 32 + (quad ^ swr) * 8];
    }
#pragma unroll
    for (int nt = 0; nt < 4; ++nt) {
      const int R = wn + nt * 16 + l15;
      wf[nt] = *(const half8*)&sW[R * 32 + (quad ^ swr) * 8];
    }
#pragma unroll
    for (int mt = 0; mt < 4; ++mt)
#pragma unroll
      for (int nt = 0; nt < 4; ++nt)
        acc[mt][nt] = __builtin_amdgcn_mfma_f32_16x16x32_f16(wf[nt], af[mt], acc[mt][nt], 0, 0, 0);
  }

  const float ysc = (mode == 0 && z == 0) ? qsc : 1.f;
#pragma unroll
  for (int mt = 0; mt < 4; ++mt)
#pragma unroll
    for (int nt = 0; nt < 4; ++nt) {
      const int m = m0 + wm + mt * 16 + l15;
      const int n = n0 + wn + nt * 16 + quad * 4;
      if (mode == 2) {
        float4 v;
        v.x = acc[mt][nt][0] + bias[n + 0];
        v.y = acc[mt][nt][1] + bias[n + 1];
        v.z = acc[mt][nt][2] + bias[n + 2];
        v.w = acc[mt][nt][3] + bias[n + 3];
        *(float4*)(Yf + (size_t)m * N + n) = v;
      } else {
        half4 hv;
#pragma unroll
        for (int r = 0; r < 4; ++r) hv[r] = (_Float16)(acc[mt][nt][r] * ysc);
        *(half4*)(Y + (size_t)m * N + n) = hv;
      }
    }
}

// ---------------------------------------------------------------------------
// V pretranspose: Vh[b][t][c] -> Vt packed per (b,h,kt) 16x64 tile such that
// lane (l15,quad) reads its 4 PV fragments as TWO half8 loads:
//   Vt[(b,h,kt)*1024 + (d&15)*64 + (k>>2)*16 + (d>>4)*4 + (k&3)]
//     = V[b][kt*16+k][h*64+d]
// ---------------------------------------------------------------------------
__global__ __launch_bounds__(256)
void transpose_v(const _Float16* __restrict__ Vh, _Float16* __restrict__ Vt) {
  constexpr int PAD = 1028;
  __shared__ _Float16 tile[16][PAD];
  const int b  = blockIdx.x >> 7;
  const int kt = blockIdx.x & 127;
  const int tid = threadIdx.x;

#pragma unroll
  for (int j = 0; j < 8; ++j) {
    const int ch = tid + 256 * j;
    const int t  = ch >> 7;
    const int c8 = ch & 127;
    *(half8*)&tile[t][c8 * 8] =
        *(const half8*)(Vh + ((size_t)b * T_ + kt * 16 + t) * C_ + c8 * 8);
  }
  __syncthreads();

#pragma unroll
  for (int j = 0; j < 8; ++j) {
    const int cc = tid + 256 * j;
    const int h  = cc >> 7;
    const int d  = (cc >> 1) & 63;
    const int th = (cc & 1) * 8;
    const int c  = h * 64 + d;
    half4 va, vb4;
#pragma unroll
    for (int i = 0; i < 4; ++i) va[i]  = tile[th + i][c];
#pragma unroll
    for (int i = 0; i < 4; ++i) vb4[i] = tile[th + 4 + i][c];
    const size_t base = (((size_t)b * H_ + h) * 128 + kt) * 1024 +
                        (size_t)((d & 15) * 64 + (th >> 2) * 16 + (d >> 4) * 4);
    *(half4*)(Vt + base) = va;
    *(half4*)(Vt + base + 16) = vb4;
  }
}

// ---------------------------------------------------------------------------
// MFMA head-softmax attention v8: SINGLE-barrier online softmax.
// r0-r3 established: not BW-bound (XCD pinning cut FETCH 3x, time flat),
// not latency-bound (prefetch schedules flat). ~72% idle => per-tile fixed
// cost (2 barriers + 2 LDS roundtrips + exact divide + setprio in lockstep
// regime) dominates the tiny 24-MFMA tile. This version:
//   - each wave writes (local head-max m_w, local sum of exp(s-m_w)) BEFORE
//     one barrier; after it, global M = max_w m_w, T = sum_w sum_w*exp(m_w-M).
//     1 barrier + 1 LDS roundtrip per tile (was 2+2); exps moved pre-barrier.
//   - no setprio (m190: negative in barrier-lockstep wave regime).
//   - fast v_rcp for 1/T (error ~1e-7 << f16 budget).
//   - XCD-local (b,split) mapping kept; plain loads/stores (no nontemporal).
// Q arrives pre-scaled by sqrt(D)=8 (folded into the projection).
// ---------------------------------------------------------------------------
__global__ __launch_bounds__(256, 2)
void attn_mfma(const _Float16* __restrict__ Qhp, const _Float16* __restrict__ Khp,
               const _Float16* __restrict__ Vtp, _Float16* __restrict__ OP) {
  __shared__ f32x4 redm[2][4][64];
  __shared__ f32x4 reds[2][4][64];

  const int tid  = threadIdx.x;
  const int lane = tid & 63;
  const int w    = tid >> 6;
  const int l15  = lane & 15;
  const int quad = lane >> 4;
  const int cell = quad * 16 + l15;

  // XCD-locality mapping: xcd = blockIdx&7 selects (b, split); all blocks on
  // one XCD share the same 2MB K-slice + 2MB V-slice (fits 4MB L2).
  const int xcd   = blockIdx.x & 7;
  const int qi    = blockIdx.x >> 3;   // 0..127
  const int b     = xcd & 1;
  const int split = xcd >> 1;          // 0..3
  const int q0    = qi << 4;

  const size_t qrow = ((size_t)b * T_ + q0 + l15) * C_;

  // hoisted Q fragments (loop-invariant): 8 half8 = 32 VGPR
  half8 qh[4][2];
#pragma unroll
  for (int hl = 0; hl < 4; ++hl)
#pragma unroll
    for (int kk = 0; kk < 2; ++kk)
      qh[hl][kk] = *(const half8*)(Qhp + qrow + (w * 4 + hl) * 64 + kk * 32 + quad * 8);

  f32x4 oacc[4][4];
#pragma unroll
  for (int hl = 0; hl < 4; ++hl)
#pragma unroll
    for (int mt = 0; mt < 4; ++mt)
      oacc[hl][mt] = (f32x4){0.f, 0.f, 0.f, 0.f};

  const int kpb  = T_ / 4;
  const int k_lo = split * kpb;
  const int jt   = kpb / 16;           // 32

  // per-lane V base: head block (w*4), lane offset folded in
  const _Float16* vbase = Vtp + ((size_t)b * H_ + w * 4) * (128 * 1024) +
                          (size_t)(l15 * 64 + quad * 16);

  for (int j = 0; j < jt; ++j) {
    const int k0 = k_lo + j * 16;
    const int kt = k0 >> 4;
    const int p  = j & 1;
    const size_t krow = ((size_t)b * T_ + k0 + l15) * C_;

    // K + V fragment loads (compiler-scheduled; L2-resident by construction)
    half8 akh[4][2];
    half8 avh[4][2];
#pragma unroll
    for (int hl = 0; hl < 4; ++hl)
#pragma unroll
      for (int kk = 0; kk < 2; ++kk)
        akh[hl][kk] = *(const half8*)(Khp + krow + (w * 4 + hl) * 64 + kk * 32 + quad * 8);
#pragma unroll
    for (int hl = 0; hl < 4; ++hl) {
      const _Float16* vb = vbase + (size_t)hl * (128 * 1024) + (size_t)kt * 1024;
      avh[hl][0] = *(const half8*)(vb);
      avh[hl][1] = *(const half8*)(vb + 8);
    }

    // S^T = K Q^T (Q pre-scaled by sqrt(D)); s[hl]: key=quad*4+r, q=l15
    f32x4 s[4];
#pragma unroll
    for (int hl = 0; hl < 4; ++hl) s[hl] = (f32x4){0.f, 0.f, 0.f, 0.f};
#pragma unroll
    for (int hl = 0; hl < 4; ++hl)
#pragma unroll
      for (int kk = 0; kk < 2; ++kk)
        s[hl] = __builtin_amdgcn_mfma_f32_16x16x32_f16(akh[hl][kk], qh[hl][kk], s[hl], 0, 0, 0);

    // local (4-head) max + exp + local sum, all BEFORE the single barrier
    const f32x4 mw = vmax4(vmax4(s[0], s[1]), vmax4(s[2], s[3]));
    redm[p][w][cell] = mw;
    f32x4 ps = (f32x4){0.f, 0.f, 0.f, 0.f};
#pragma unroll
    for (int hl = 0; hl < 4; ++hl)
#pragma unroll
      for (int r = 0; r < 4; ++r) {
        const float ev = __expf(s[hl][r] - mw[r]);
        s[hl][r] = ev;                 // e relative to LOCAL max
        ps[r] += ev;
      }
    reds[p][w][cell] = ps;
    lds_barrier();                     // the ONLY barrier per tile

    // global max + rescaled global sum across the 4 waves
    f32x4 wm0 = redm[p][0][cell], wm1 = redm[p][1][cell];
    f32x4 wm2 = redm[p][2][cell], wm3 = redm[p][3][cell];
    const f32x4 gm = vmax4(vmax4(wm0, wm1), vmax4(wm2, wm3));
    f32x4 ex0, ex1, ex2, ex3;
#pragma unroll
    for (int r = 0; r < 4; ++r) {
      ex0[r] = __expf(wm0[r] - gm[r]);
      ex1[r] = __expf(wm1[r] - gm[r]);
      ex2[r] = __expf(wm2[r] - gm[r]);
      ex3[r] = __expf(wm3[r] - gm[r]);
    }
    const f32x4 t = reds[p][0][cell] * ex0 + reds[p][1][cell] * ex1 +
                    reds[p][2][cell] * ex2 + reds[p][3][cell] * ex3;
    const f32x4 exo = (w == 0) ? ex0 : (w == 1) ? ex1 : (w == 2) ? ex2 : ex3;
    f32x4 f;
#pragma unroll
    for (int r = 0; r < 4; ++r)
      f[r] = exo[r] * __builtin_amdgcn_rcpf(t[r]);

    half4 pf[4];
#pragma unroll
    for (int hl = 0; hl < 4; ++hl)
#pragma unroll
      for (int r = 0; r < 4; ++r)
        pf[hl][r] = (_Float16)(s[hl][r] * f[r]);

    // O^T += V^T P^T
#pragma unroll
    for (int hl = 0; hl < 4; ++hl) {
      const half4 v0 = __builtin_shufflevector(avh[hl][0], avh[hl][0], 0, 1, 2, 3);
      const half4 v1 = __builtin_shufflevector(avh[hl][0], avh[hl][0], 4, 5, 6, 7);
      const half4 v2 = __builtin_shufflevector(avh[hl][1], avh[hl][1], 0, 1, 2, 3);
      const half4 v3 = __builtin_shufflevector(avh[hl][1], avh[hl][1], 4, 5, 6, 7);
      oacc[hl][0] = __builtin_amdgcn_mfma_f32_16x16x16f16(v0, pf[hl], oacc[hl][0], 0, 0, 0);
      oacc[hl][1] = __builtin_amdgcn_mfma_f32_16x16x16f16(v1, pf[hl], oacc[hl][1], 0, 0, 0);
      oacc[hl][2] = __builtin_amdgcn_mfma_f32_16x16x16f16(v2, pf[hl], oacc[hl][2], 0, 0, 0);
      oacc[hl][3] = __builtin_amdgcn_mfma_f32_16x16x16f16(v3, pf[hl], oacc[hl][3], 0, 0, 0);
    }
  }

  _Float16* op = OP + (size_t)split * ((size_t)B_ * T_ * C_);
  const size_t orow = ((size_t)b * T_ + q0 + l15) * C_;
#pragma unroll
  for (int hl = 0; hl < 4; ++hl)
#pragma unroll
    for (int mt = 0; mt < 4; ++mt) {
      half4 hv;
#pragma unroll
      for (int r = 0; r < 4; ++r) hv[r] = (_Float16)oacc[hl][mt][r];
      *(half4*)(op + orow + (w * 4 + hl) * 64 + mt * 16 + quad * 4) = hv;
    }
}

// ---------------------------------------------------------------------------
// AOh = (f16) sum over splits of f16 OP[s]  (fp32 accumulate)
// ---------------------------------------------------------------------------
__global__ __launch_bounds__(256)
void reduce_oh(const _Float16* __restrict__ OP, _Float16* __restrict__ AOh,
               int nsplit, size_t n) {
  const size_t i = ((size_t)blockIdx.x * 256 + threadIdx.x) * 8;
  float a[8] = {};
  for (int s = 0; s < nsplit; ++s) {
    const half8 v = *(const half8*)(OP + (size_t)s * n + i);
#pragma unroll
    for (int r = 0; r < 8; ++r) a[r] += (float)v[r];
  }
  half8 o;
#pragma unroll
  for (int r = 0; r < 8; ++r) o[r] = (_Float16)a[r];
  *(half8*)(AOh + i) = o;
}

}  // namespace

extern "C" void kernel_launch(void* const* d_in, const int* in_sizes, int n_in,
                              void* d_out, int out_size, void* d_ws, size_t ws_size,
                              hipStream_t stream) {
  const float* xq = (const float*)d_in[0];
  const float* xk = (const float*)d_in[1];
  const float* xv = (const float*)d_in[2];
  const float* Wq = (const float*)d_in[3];
  const float* Wk = (const float*)d_in[4];
  const float* Wv = (const float*)d_in[5];
  const float* Wo = (const float*)d_in[6];
  const float* bo = (const float*)d_in[7];
  float* out = (float*)d_out;

  const size_t MB   = 1ull << 20;
  const size_t nBTC = (size_t)B_ * T_ * C_;  // 4M elements

  char* wsb = (char*)d_ws;
  _Float16* Qh  = (_Float16*)(wsb + 0 * MB);
  _Float16* Kh  = (_Float16*)(wsb + 8 * MB);
  _Float16* Vt  = (_Float16*)(wsb + 16 * MB);
  _Float16* vh  = (_Float16*)(wsb + 24 * MB);
  _Float16* AOh = (_Float16*)(wsb + 24 * MB);
  _Float16* xqh = (_Float16*)(wsb + 32 * MB);
  _Float16* xkh = (_Float16*)(wsb + 40 * MB);
  _Float16* xvh = (_Float16*)(wsb + 48 * MB);
  _Float16* OP  = (_Float16*)(wsb + 32 * MB);
  _Float16* Wqh = (_Float16*)(wsb + 64 * MB);
  _Float16* Wkh = (_Float16*)(wsb + 66 * MB);
  _Float16* Wvh = (_Float16*)(wsb + 68 * MB);
  _Float16* Woh = (_Float16*)(wsb + 70 * MB);

  const int nsplit = 4;
  const int M = B_ * T_;                     // 4096
  dim3 blk(256);

  // 1) cast all 7 fp32 inputs to f16 (16M elements)
  cast7<<<dim3(8192), blk, 0, stream>>>(xq, xk, xv, Wq, Wk, Wv, Wo,
                                        xqh, xkh, xvh, Wqh, Wkh, Wvh, Woh);

  // 2) three projections, z-batched; Q pre-scaled by sqrt(D)=8 (quirk)
  gemm_f16nt<<<dim3(C_ / 128, M / 128, 3), blk, 0, stream>>>(
      xqh, xkh, xvh, Wqh, Wkh, Wvh, Qh, Kh, vh,
      nullptr, nullptr, C_, C_, 0, 8.f);

  // 3) V pretranspose (packed PV-fragment layout)
  transpose_v<<<dim3(B_ * 128), blk, 0, stream>>>(vh, Vt);

  // 4) fused head-softmax attention (split-k x4, single-barrier softmax)
  attn_mfma<<<dim3(B_ * (T_ / 16) * nsplit), blk, 0, stream>>>(Qh, Kh, Vt, OP);

  // 5) split reduction -> f16 AO
  reduce_oh<<<dim3((unsigned)(nBTC / 2048)), blk, 0, stream>>>(OP, AOh, nsplit, nBTC);

  // 6) output projection + bias -> fp32 out
  gemm_f16nt<<<dim3(C_ / 128, M / 128, 1), blk, 0, stream>>>(
      AOh, nullptr, nullptr, Woh, nullptr, nullptr, nullptr, nullptr, nullptr,
      out, bo, C_, C_, 2, 1.f);
}